// Round 1
// baseline (4903.749 us; speedup 1.0000x reference)
//
#include <hip/hip_runtime.h>
#include <cstddef>

#define LSEQ    1024
#define DMODEL  256
#define DINNER  512
#define DSTATE  64
#define NHEADS  8
#define HEADDIM 64
#define CONVDIM 640
#define DINPROJ 1160
#define ROWS    2048   // B * L
#define EPSF    1e-5f

__device__ __forceinline__ float sigmoidf_(float x) { return 1.0f / (1.0f + expf(-x)); }
__device__ __forceinline__ float siluf_(float x)    { return x / (1.0f + expf(-x)); }
__device__ __forceinline__ float softplusf_(float x) {
    return x > 0.0f ? x + log1pf(expf(-x)) : log1pf(expf(x));
}

// ---------------------------------------------------------------- embedding
__global__ __launch_bounds__(256) void embed_kernel(
    const int* __restrict__ ids, const float* __restrict__ mask,
    const float* __restrict__ tok, const float* __restrict__ pos,
    float* __restrict__ u0, float* __restrict__ u1) {
    int row = blockIdx.x;            // b*1024 + t
    int d = threadIdx.x;
    int b = row >> 10, t = row & 1023;
    int id = ids[row];
    float v = tok[(size_t)id * DMODEL + d] + pos[(size_t)t * DMODEL + d];
    v *= mask[row];
    u0[(size_t)row * DMODEL + d] = v;
    u1[((size_t)(b << 10) + (1023 - t)) * DMODEL + d] = v;   // time-flipped copy
}

// ---------------------------------------------------------------- GEMM  C[M,N] = A[M,K] * W[N,K]^T   (per-direction via blockIdx.z)
#define BM 64
#define BN 64
#define BKK 16
__global__ __launch_bounds__(256) void gemm_nt(
    const float* __restrict__ A, const float* __restrict__ W, float* __restrict__ C,
    int M, int N, int K, long sA, long sW, long sC) {
    int dir = blockIdx.z;
    A += (size_t)dir * sA; W += (size_t)dir * sW; C += (size_t)dir * sC;
    __shared__ float As[BKK][BM + 8];
    __shared__ float Bs[BKK][BN + 8];
    int tid = threadIdx.x;
    int tx = tid & 15, ty = tid >> 4;
    int m0 = blockIdx.x * BM, n0 = blockIdx.y * BN;
    float acc[4][4] = {{0.f}};
    int srow = tid >> 2, sseg = tid & 3;       // 64 rows x 4 segments of 4 floats

    for (int k0 = 0; k0 < K; k0 += BKK) {
        float4 av = *(const float4*)&A[(size_t)(m0 + srow) * K + k0 + sseg * 4];
        As[sseg * 4 + 0][srow] = av.x; As[sseg * 4 + 1][srow] = av.y;
        As[sseg * 4 + 2][srow] = av.z; As[sseg * 4 + 3][srow] = av.w;
        int bj = n0 + srow;
        float4 bv = make_float4(0.f, 0.f, 0.f, 0.f);
        if (bj < N) bv = *(const float4*)&W[(size_t)bj * K + k0 + sseg * 4];
        Bs[sseg * 4 + 0][srow] = bv.x; Bs[sseg * 4 + 1][srow] = bv.y;
        Bs[sseg * 4 + 2][srow] = bv.z; Bs[sseg * 4 + 3][srow] = bv.w;
        __syncthreads();
#pragma unroll
        for (int k = 0; k < BKK; ++k) {
            float4 a4 = *(const float4*)&As[k][ty * 4];
            float4 b4 = *(const float4*)&Bs[k][tx * 4];
            float a_[4] = {a4.x, a4.y, a4.z, a4.w};
            float b_[4] = {b4.x, b4.y, b4.z, b4.w};
#pragma unroll
            for (int i = 0; i < 4; ++i)
#pragma unroll
                for (int j = 0; j < 4; ++j) acc[i][j] = fmaf(a_[i], b_[j], acc[i][j]);
        }
        __syncthreads();
    }
#pragma unroll
    for (int i = 0; i < 4; ++i) {
        int m = m0 + ty * 4 + i;
#pragma unroll
        for (int j = 0; j < 4; ++j) {
            int n = n0 + tx * 4 + j;
            if (n < N) C[(size_t)m * N + n] = acc[i][j];
        }
    }
}

// ---------------------------------------------------------------- depthwise causal conv(4) + SiLU, plus softplus(dt)
__global__ __launch_bounds__(256) void conv_dt_kernel(
    const float* __restrict__ zx, float* __restrict__ xc, float* __restrict__ dts,
    const float* __restrict__ cw, const float* __restrict__ cb,
    const float* __restrict__ dtb, int layer) {
    int row = blockIdx.x;            // b*1024+t
    int dir = blockIdx.y;
    int b = row >> 10, t = row & 1023;
    const float* zxd = zx + (size_t)dir * ROWS * DINPROJ;
    int pi = dir * 2 + layer;
    const float* cwl = cw + (size_t)pi * CONVDIM * 4;
    const float* cbl = cb + (size_t)pi * CONVDIM;
    const float* dtbl = dtb + pi * NHEADS;
    for (int c = threadIdx.x; c < CONVDIM + NHEADS; c += 256) {
        if (c < CONVDIM) {
            float acc = cbl[c];
#pragma unroll
            for (int k = 0; k < 4; ++k) {
                int tt = t - 3 + k;
                if (tt >= 0)
                    acc = fmaf(zxd[(size_t)((b << 10) + tt) * DINPROJ + DINNER + c], cwl[c * 4 + k], acc);
            }
            xc[((size_t)dir * ROWS + row) * CONVDIM + c] = siluf_(acc);
        } else {
            int hh = c - CONVDIM;
            dts[((size_t)dir * ROWS + row) * NHEADS + hh] =
                softplusf_(zxd[(size_t)row * DINPROJ + DINNER + CONVDIM + hh] + dtbl[hh]);
        }
    }
}

// ---------------------------------------------------------------- sequential SSM scan: one wave per (dir,b,head)
__global__ __launch_bounds__(64) void scan_kernel(
    const float* __restrict__ xc, const float* __restrict__ dts, float* __restrict__ y,
    const float* __restrict__ Alog, const float* __restrict__ Dp, int layer) {
    int u = blockIdx.x;              // 0..31
    int dir = u >> 4, b = (u >> 3) & 1, h = u & 7;
    int p = threadIdx.x;             // headdim lane
    int pi = dir * 2 + layer;
    float Av = -expf(Alog[pi * NHEADS + h]);
    float Dv = Dp[pi * NHEADS + h];
    const float* xcd = xc + (size_t)dir * ROWS * CONVDIM;
    const float* dtd = dts + (size_t)dir * ROWS * NHEADS;
    float* yd = y + (size_t)dir * ROWS * DINNER;
    float hreg[DSTATE];
#pragma unroll
    for (int n = 0; n < DSTATE; ++n) hreg[n] = 0.f;
    int base = b << 10;
    for (int t = 0; t < LSEQ; ++t) {
        int row = base + t;
        const float* rowp = xcd + (size_t)row * CONVDIM;
        float dtv = dtd[row * NHEADS + h];         // wave-uniform
        float dA = expf(dtv * Av);                 // wave-uniform
        float xv = rowp[h * HEADDIM + p];
        float coef = dtv * xv;
        const float* Bp = rowp + DINNER;           // wave-uniform base
        const float* Cp = rowp + DINNER + DSTATE;
        float y0 = 0.f, y1 = 0.f, y2 = 0.f, y3 = 0.f;
#pragma unroll
        for (int n = 0; n < DSTATE; n += 4) {
            float b0 = Bp[n], b1 = Bp[n + 1], b2 = Bp[n + 2], b3 = Bp[n + 3];
            float c0 = Cp[n], c1 = Cp[n + 1], c2 = Cp[n + 2], c3 = Cp[n + 3];
            hreg[n]     = fmaf(hreg[n],     dA, coef * b0); y0 = fmaf(hreg[n],     c0, y0);
            hreg[n + 1] = fmaf(hreg[n + 1], dA, coef * b1); y1 = fmaf(hreg[n + 1], c1, y1);
            hreg[n + 2] = fmaf(hreg[n + 2], dA, coef * b2); y2 = fmaf(hreg[n + 2], c2, y2);
            hreg[n + 3] = fmaf(hreg[n + 3], dA, coef * b3); y3 = fmaf(hreg[n + 3], c3, y3);
        }
        yd[(size_t)row * DINNER + h * HEADDIM + p] = (y0 + y1) + (y2 + y3) + Dv * xv;
    }
}

// ---------------------------------------------------------------- y * silu(z), RMSNorm * norm_w   (in place on y)
__global__ __launch_bounds__(256) void gate_rms_kernel(
    float* __restrict__ y, const float* __restrict__ zx,
    const float* __restrict__ nw, int layer) {
    int row = blockIdx.x;
    int dir = blockIdx.y;
    const float* zrow = zx + ((size_t)dir * ROWS + row) * DINPROJ;
    float* yrow = y + ((size_t)dir * ROWS + row) * DINNER;
    const float* nwl = nw + (dir * 2 + layer) * DINNER;
    int tid = threadIdx.x;
    int i0 = tid, i1 = tid + 256;
    float g0 = yrow[i0] * siluf_(zrow[i0]);
    float g1 = yrow[i1] * siluf_(zrow[i1]);
    __shared__ float red[256];
    red[tid] = fmaf(g0, g0, g1 * g1);
    __syncthreads();
    for (int s = 128; s > 0; s >>= 1) {
        if (tid < s) red[tid] += red[tid + s];
        __syncthreads();
    }
    float scale = 1.0f / sqrtf(red[0] / (float)DINNER + EPSF);
    yrow[i0] = g0 * scale * nwl[i0];
    yrow[i1] = g1 * scale * nwl[i1];
}

// ---------------------------------------------------------------- fusion gate + LayerNorm -> out
__global__ __launch_bounds__(256) void fusion_ln_kernel(
    const float* __restrict__ u0, const float* __restrict__ u1,
    const float* __restrict__ fw, const float* __restrict__ fb,
    const float* __restrict__ lnw, const float* __restrict__ lnb,
    float* __restrict__ out) {
    int row = blockIdx.x;
    int b = row >> 10, t = row & 1023;
    int tid = threadIdx.x;
    __shared__ float comb[2 * DMODEL];
    float f = u0[(size_t)row * DMODEL + tid];
    float bw = u1[((size_t)(b << 10) + (1023 - t)) * DMODEL + tid];  // un-flip bwd
    comb[tid] = f;
    comb[DMODEL + tid] = bw;
    __syncthreads();
    float a0 = fb[tid], a1 = fb[DMODEL + tid];
    const float* w0 = fw + (size_t)tid * (2 * DMODEL);
    const float* w1 = fw + (size_t)(DMODEL + tid) * (2 * DMODEL);
    for (int k = 0; k < 2 * DMODEL; ++k) {
        float cv = comb[k];
        a0 = fmaf(cv, w0[k], a0);
        a1 = fmaf(cv, w1[k], a1);
    }
    float fused = sigmoidf_(a0) * f + sigmoidf_(a1) * bw;
    __shared__ float red[256];
    red[tid] = fused;
    __syncthreads();
    for (int s = 128; s > 0; s >>= 1) {
        if (tid < s) red[tid] += red[tid + s];
        __syncthreads();
    }
    float mu = red[0] / (float)DMODEL;
    __syncthreads();
    float d = fused - mu;
    red[tid] = d * d;
    __syncthreads();
    for (int s = 128; s > 0; s >>= 1) {
        if (tid < s) red[tid] += red[tid + s];
        __syncthreads();
    }
    float var = red[0] / (float)DMODEL;
    out[(size_t)row * DMODEL + tid] = d * (1.0f / sqrtf(var + EPSF)) * lnw[tid] + lnb[tid];
}

// ---------------------------------------------------------------- launch
extern "C" void kernel_launch(void* const* d_in, const int* in_sizes, int n_in,
                              void* d_out, int out_size, void* d_ws, size_t ws_size,
                              hipStream_t stream) {
    const int*   ids  = (const int*)d_in[0];
    const float* mask = (const float*)d_in[1];
    const float* tok  = (const float*)d_in[2];
    const float* pos  = (const float*)d_in[3];
    const float* inw  = (const float*)d_in[4];
    const float* cw   = (const float*)d_in[5];
    const float* cb   = (const float*)d_in[6];
    const float* dtb  = (const float*)d_in[7];
    const float* alog = (const float*)d_in[8];
    const float* dpar = (const float*)d_in[9];
    const float* nw   = (const float*)d_in[10];
    const float* ow   = (const float*)d_in[11];
    const float* fw   = (const float*)d_in[12];
    const float* fb   = (const float*)d_in[13];
    const float* lnw  = (const float*)d_in[14];
    const float* lnb  = (const float*)d_in[15];

    float* ws   = (float*)d_ws;
    float* ubuf = ws;                                        // 2 * 2048 * 256
    float* zx   = ubuf + (size_t)2 * ROWS * DMODEL;          // 2 * 2048 * 1160
    float* xc   = zx   + (size_t)2 * ROWS * DINPROJ;         // 2 * 2048 * 640
    float* dts  = xc   + (size_t)2 * ROWS * CONVDIM;         // 2 * 2048 * 8
    float* ybuf = dts  + (size_t)2 * ROWS * NHEADS;          // 2 * 2048 * 512

    embed_kernel<<<ROWS, DMODEL, 0, stream>>>(ids, mask, tok, pos, ubuf, ubuf + (size_t)ROWS * DMODEL);

    for (int layer = 0; layer < 2; ++layer) {
        dim3 g1(ROWS / BM, (DINPROJ + BN - 1) / BN, 2);
        gemm_nt<<<g1, 256, 0, stream>>>(ubuf, inw + (size_t)layer * DINPROJ * DMODEL, zx,
                                        ROWS, DINPROJ, DMODEL,
                                        (long)ROWS * DMODEL, (long)2 * DINPROJ * DMODEL, (long)ROWS * DINPROJ);
        conv_dt_kernel<<<dim3(ROWS, 2), 256, 0, stream>>>(zx, xc, dts, cw, cb, dtb, layer);
        scan_kernel<<<32, 64, 0, stream>>>(xc, dts, ybuf, alog, dpar, layer);
        gate_rms_kernel<<<dim3(ROWS, 2), 256, 0, stream>>>(ybuf, zx, nw, layer);
        dim3 g2(ROWS / BM, DMODEL / BN, 2);
        gemm_nt<<<g2, 256, 0, stream>>>(ybuf, ow + (size_t)layer * DMODEL * DINNER, ubuf,
                                        ROWS, DMODEL, DINNER,
                                        (long)ROWS * DINNER, (long)2 * DMODEL * DINNER, (long)ROWS * DMODEL);
    }

    fusion_ln_kernel<<<ROWS, DMODEL, 0, stream>>>(ubuf, ubuf + (size_t)ROWS * DMODEL,
                                                  fw, fb, lnw, lnb, (float*)d_out);
}

// Round 2
// 553.440 us; speedup vs baseline: 8.8605x; 8.8605x over previous
//
#include <hip/hip_runtime.h>
#include <cstddef>

#define LSEQ    1024
#define DMODEL  256
#define DINNER  512
#define DSTATE  64
#define NHEADS  8
#define HEADDIM 64
#define CONVDIM 640
#define DINPROJ 1160
#define ROWS    2048   // B * L
#define EPSF    1e-5f
#define NC      16     // chunks per sequence
#define LC      64     // chunk length
#define XBCW    648    // xBC (640) + raw dt (8)

__device__ __forceinline__ float sigmoidf_(float x) { return 1.0f / (1.0f + expf(-x)); }
__device__ __forceinline__ float siluf_(float x)    { return x / (1.0f + expf(-x)); }
__device__ __forceinline__ float softplusf_(float x) {
    return x > 0.0f ? x + log1pf(expf(-x)) : log1pf(expf(x));
}

// ---------------------------------------------------------------- embedding
__global__ __launch_bounds__(256) void embed_kernel(
    const int* __restrict__ ids, const float* __restrict__ mask,
    const float* __restrict__ tok, const float* __restrict__ pos,
    float* __restrict__ u0, float* __restrict__ u1) {
    int row = blockIdx.x;            // b*1024 + t
    int d = threadIdx.x;
    int b = row >> 10, t = row & 1023;
    int id = ids[row];
    float v = tok[(size_t)id * DMODEL + d] + pos[(size_t)t * DMODEL + d];
    v *= mask[row];
    u0[(size_t)row * DMODEL + d] = v;
    u1[((size_t)(b << 10) + (1023 - t)) * DMODEL + d] = v;   // time-flipped copy
}

// ---------------------------------------------------------------- GEMM  C = A[M,K] * W[N,K]^T, split column output
#define BM 64
#define BN 64
#define BKK 16
__global__ __launch_bounds__(256) void gemm_nt(
    const float* __restrict__ A, const float* __restrict__ W,
    float* __restrict__ C0, float* __restrict__ C1,
    int M, int N, int K, int Nsplit, int ld0, int ld1,
    long sA, long sW, long sC0, long sC1) {
    int dir = blockIdx.z;
    A += (size_t)dir * sA; W += (size_t)dir * sW;
    C0 += (size_t)dir * sC0; C1 += (size_t)dir * sC1;
    __shared__ float As[BKK][BM + 8];
    __shared__ float Bs[BKK][BN + 8];
    int tid = threadIdx.x;
    int tx = tid & 15, ty = tid >> 4;
    int m0 = blockIdx.x * BM, n0 = blockIdx.y * BN;
    float acc[4][4] = {{0.f}};
    int srow = tid >> 2, sseg = tid & 3;       // 64 rows x 4 segments of 4 floats

    for (int k0 = 0; k0 < K; k0 += BKK) {
        float4 av = *(const float4*)&A[(size_t)(m0 + srow) * K + k0 + sseg * 4];
        As[sseg * 4 + 0][srow] = av.x; As[sseg * 4 + 1][srow] = av.y;
        As[sseg * 4 + 2][srow] = av.z; As[sseg * 4 + 3][srow] = av.w;
        int bj = n0 + srow;
        float4 bv = make_float4(0.f, 0.f, 0.f, 0.f);
        if (bj < N) bv = *(const float4*)&W[(size_t)bj * K + k0 + sseg * 4];
        Bs[sseg * 4 + 0][srow] = bv.x; Bs[sseg * 4 + 1][srow] = bv.y;
        Bs[sseg * 4 + 2][srow] = bv.z; Bs[sseg * 4 + 3][srow] = bv.w;
        __syncthreads();
#pragma unroll
        for (int k = 0; k < BKK; ++k) {
            float4 a4 = *(const float4*)&As[k][ty * 4];
            float4 b4 = *(const float4*)&Bs[k][tx * 4];
            float a_[4] = {a4.x, a4.y, a4.z, a4.w};
            float b_[4] = {b4.x, b4.y, b4.z, b4.w};
#pragma unroll
            for (int i = 0; i < 4; ++i)
#pragma unroll
                for (int j = 0; j < 4; ++j) acc[i][j] = fmaf(a_[i], b_[j], acc[i][j]);
        }
        __syncthreads();
    }
#pragma unroll
    for (int i = 0; i < 4; ++i) {
        int m = m0 + ty * 4 + i;
#pragma unroll
        for (int j = 0; j < 4; ++j) {
            int n = n0 + tx * 4 + j;
            if (n < N) {
                if (n < Nsplit) C0[(size_t)m * ld0 + n] = acc[i][j];
                else            C1[(size_t)m * ld1 + (n - Nsplit)] = acc[i][j];
            }
        }
    }
}

// ---------------------------------------------------------------- depthwise causal conv(4) + SiLU, plus softplus(dt)
// xbc layout: [dir][row][648] = xBC_raw(640) ++ dt_raw(8)
__global__ __launch_bounds__(256) void conv_dt_kernel(
    const float* __restrict__ xbc, float* __restrict__ xc, float* __restrict__ dts,
    const float* __restrict__ cw, const float* __restrict__ cb,
    const float* __restrict__ dtb, int layer) {
    int row = blockIdx.x;            // b*1024+t
    int dir = blockIdx.y;
    int b = row >> 10, t = row & 1023;
    const float* xd = xbc + (size_t)dir * ROWS * XBCW;
    int pi = dir * 2 + layer;
    const float* cwl = cw + (size_t)pi * CONVDIM * 4;
    const float* cbl = cb + (size_t)pi * CONVDIM;
    const float* dtbl = dtb + pi * NHEADS;
    for (int c = threadIdx.x; c < CONVDIM + NHEADS; c += 256) {
        if (c < CONVDIM) {
            float acc = cbl[c];
#pragma unroll
            for (int k = 0; k < 4; ++k) {
                int tt = t - 3 + k;
                if (tt >= 0)
                    acc = fmaf(xd[(size_t)((b << 10) + tt) * XBCW + c], cwl[c * 4 + k], acc);
            }
            xc[((size_t)dir * ROWS + row) * CONVDIM + c] = siluf_(acc);
        } else {
            int hh = c - CONVDIM;
            dts[((size_t)dir * ROWS + row) * NHEADS + hh] =
                softplusf_(xd[(size_t)row * XBCW + CONVDIM + hh] + dtbl[hh]);
        }
    }
}

// ---------------------------------------------------------------- S1: local chunk scan (from zero state)
// block = u*NC + c, u = dir*16 + b*8 + h; 64 threads (lane = p)
__global__ __launch_bounds__(64) void scan_chunk_kernel(
    const float* __restrict__ xc, const float* __restrict__ dts,
    float* __restrict__ y, const float* __restrict__ Alog, const float* __restrict__ Dp,
    float* __restrict__ H, float* __restrict__ cumb, int layer) {
    __shared__ float sBC[LC * 128];
    int blk = blockIdx.x;
    int u = blk >> 4, c = blk & 15;
    int dir = u >> 4, b = (u >> 3) & 1, h = u & 7;
    int p = threadIdx.x;
    int pi = dir * 2 + layer;
    float Av = -expf(Alog[pi * NHEADS + h]);
    float Dv = Dp[pi * NHEADS + h];
    const float* xcd = xc + (size_t)dir * ROWS * CONVDIM;
    const float* dtd = dts + (size_t)dir * ROWS * NHEADS;
    float* yd = y + (size_t)dir * ROWS * DINNER;
    int t0 = c * LC, base = b << 10;
    // stage the chunk's B/C (xc cols 512..639) into LDS: 64 rows x 128 floats
#pragma unroll
    for (int j = 0; j < 32; ++j) {
        int f4 = j * 64 + p;
        int trow = f4 >> 5, col4 = f4 & 31;
        float4 v = *(const float4*)&xcd[(size_t)(base + t0 + trow) * CONVDIM + DINNER + col4 * 4];
        *(float4*)&sBC[trow * 128 + col4 * 4] = v;
    }
    __syncthreads();
    float hreg[DSTATE];
#pragma unroll
    for (int n = 0; n < DSTATE; ++n) hreg[n] = 0.f;
    float cum = 1.0f;
    for (int tt = 0; tt < LC; ++tt) {
        int row = base + t0 + tt;
        float dtv = dtd[row * NHEADS + h];
        float xv = xcd[(size_t)row * CONVDIM + h * HEADDIM + p];
        float dA = expf(dtv * Av);
        cum *= dA;
        if (p == 0) cumb[(u << 10) + t0 + tt] = cum;
        float coef = dtv * xv;
        const float* Bs = &sBC[tt * 128];
        const float* Cs = Bs + 64;
        float y0 = 0.f, y1 = 0.f, y2 = 0.f, y3 = 0.f;
#pragma unroll
        for (int n = 0; n < DSTATE; n += 4) {
            float4 b4 = *(const float4*)&Bs[n];
            float4 c4 = *(const float4*)&Cs[n];
            hreg[n]     = fmaf(hreg[n],     dA, coef * b4.x); y0 = fmaf(hreg[n],     c4.x, y0);
            hreg[n + 1] = fmaf(hreg[n + 1], dA, coef * b4.y); y1 = fmaf(hreg[n + 1], c4.y, y1);
            hreg[n + 2] = fmaf(hreg[n + 2], dA, coef * b4.z); y2 = fmaf(hreg[n + 2], c4.z, y2);
            hreg[n + 3] = fmaf(hreg[n + 3], dA, coef * b4.w); y3 = fmaf(hreg[n + 3], c4.w, y3);
        }
        yd[(size_t)row * DINNER + h * HEADDIM + p] = (y0 + y1) + (y2 + y3) + Dv * xv;
    }
    // write chunk-final local state: H[blk][p*64 + n]
    float* Hb = H + (size_t)blk * 4096 + p * 64;
#pragma unroll
    for (int n = 0; n < DSTATE; n += 4)
        *(float4*)&Hb[n] = make_float4(hreg[n], hreg[n + 1], hreg[n + 2], hreg[n + 3]);
}

// ---------------------------------------------------------------- S2: carry chain over chunks (in place: h_end -> h_in)
__global__ __launch_bounds__(256) void carry_kernel(
    float* __restrict__ H, const float* __restrict__ cumb) {
    int u = blockIdx.x;
    int tid = threadIdx.x;
    float carry[16];
#pragma unroll
    for (int j = 0; j < 16; ++j) carry[j] = 0.f;
    for (int c = 0; c < NC; ++c) {
        float P = cumb[(u << 10) + c * LC + (LC - 1)];
        float* Hb = H + (size_t)(u * NC + c) * 4096 + tid * 16;
#pragma unroll
        for (int j = 0; j < 16; j += 4) {
            float4 e = *(const float4*)&Hb[j];
            *(float4*)&Hb[j] = make_float4(carry[j], carry[j + 1], carry[j + 2], carry[j + 3]);
            carry[j]     = fmaf(P, carry[j],     e.x);
            carry[j + 1] = fmaf(P, carry[j + 1], e.y);
            carry[j + 2] = fmaf(P, carry[j + 2], e.z);
            carry[j + 3] = fmaf(P, carry[j + 3], e.w);
        }
    }
}

// ---------------------------------------------------------------- S3: y[t] += cum[t] * (C_t . h_in), chunks 1..NC-1
__global__ __launch_bounds__(64) void fix_kernel(
    const float* __restrict__ xc, float* __restrict__ y,
    const float* __restrict__ H, const float* __restrict__ cumb) {
    __shared__ float sC[LC * 64];
    int blk = blockIdx.x;
    int u = blk / (NC - 1);
    int c = blk % (NC - 1) + 1;
    int dir = u >> 4, b = (u >> 3) & 1, h = u & 7;
    int p = threadIdx.x;
    const float* xcd = xc + (size_t)dir * ROWS * CONVDIM;
    float* yd = y + (size_t)dir * ROWS * DINNER;
    int t0 = c * LC, base = b << 10;
    // stage C (xc cols 576..639): 64 rows x 64 floats
#pragma unroll
    for (int j = 0; j < 16; ++j) {
        int f4 = j * 64 + p;
        int trow = f4 >> 4, col4 = f4 & 15;
        float4 v = *(const float4*)&xcd[(size_t)(base + t0 + trow) * CONVDIM + DINNER + DSTATE + col4 * 4];
        *(float4*)&sC[trow * 64 + col4 * 4] = v;
    }
    __syncthreads();
    const float* Hb = H + (size_t)(u * NC + c) * 4096 + p * 64;
    float hin[DSTATE];
#pragma unroll
    for (int n = 0; n < DSTATE; n += 4) {
        float4 v = *(const float4*)&Hb[n];
        hin[n] = v.x; hin[n + 1] = v.y; hin[n + 2] = v.z; hin[n + 3] = v.w;
    }
    for (int tt = 0; tt < LC; ++tt) {
        int row = base + t0 + tt;
        float cumt = cumb[(u << 10) + t0 + tt];
        const float* Cs = &sC[tt * 64];
        float y0 = 0.f, y1 = 0.f, y2 = 0.f, y3 = 0.f;
#pragma unroll
        for (int n = 0; n < DSTATE; n += 4) {
            y0 = fmaf(hin[n],     Cs[n],     y0);
            y1 = fmaf(hin[n + 1], Cs[n + 1], y1);
            y2 = fmaf(hin[n + 2], Cs[n + 2], y2);
            y3 = fmaf(hin[n + 3], Cs[n + 3], y3);
        }
        size_t yi = (size_t)row * DINNER + h * HEADDIM + p;
        yd[yi] += cumt * ((y0 + y1) + (y2 + y3));
    }
}

// ---------------------------------------------------------------- y * silu(z), RMSNorm * norm_w   (in place on y)
__global__ __launch_bounds__(256) void gate_rms_kernel(
    float* __restrict__ y, const float* __restrict__ zbuf,
    const float* __restrict__ nw, int layer) {
    int row = blockIdx.x;
    int dir = blockIdx.y;
    const float* zrow = zbuf + ((size_t)dir * ROWS + row) * DINNER;
    float* yrow = y + ((size_t)dir * ROWS + row) * DINNER;
    const float* nwl = nw + (dir * 2 + layer) * DINNER;
    int tid = threadIdx.x;
    int i0 = tid, i1 = tid + 256;
    float g0 = yrow[i0] * siluf_(zrow[i0]);
    float g1 = yrow[i1] * siluf_(zrow[i1]);
    __shared__ float red[256];
    red[tid] = fmaf(g0, g0, g1 * g1);
    __syncthreads();
    for (int s = 128; s > 0; s >>= 1) {
        if (tid < s) red[tid] += red[tid + s];
        __syncthreads();
    }
    float scale = 1.0f / sqrtf(red[0] / (float)DINNER + EPSF);
    yrow[i0] = g0 * scale * nwl[i0];
    yrow[i1] = g1 * scale * nwl[i1];
}

// ---------------------------------------------------------------- fusion: build comb = [fwd, unflip(bwd)]
__global__ __launch_bounds__(256) void concat_kernel(
    const float* __restrict__ u0, const float* __restrict__ u1, float* __restrict__ comb) {
    int row = blockIdx.x;
    int tid = threadIdx.x;
    int b = row >> 10, t = row & 1023;
    comb[(size_t)row * 512 + tid] = u0[(size_t)row * DMODEL + tid];
    comb[(size_t)row * 512 + 256 + tid] = u1[((size_t)(b << 10) + (1023 - t)) * DMODEL + tid];
}

// ---------------------------------------------------------------- fusion gates + LayerNorm
__global__ __launch_bounds__(256) void fusion_ln2_kernel(
    const float* __restrict__ comb, const float* __restrict__ gate,
    const float* __restrict__ fb, const float* __restrict__ lnw,
    const float* __restrict__ lnb, float* __restrict__ out) {
    int row = blockIdx.x;
    int tid = threadIdx.x;
    float f  = comb[(size_t)row * 512 + tid];
    float bw = comb[(size_t)row * 512 + 256 + tid];
    float g0 = sigmoidf_(gate[(size_t)row * 512 + tid] + fb[tid]);
    float g1 = sigmoidf_(gate[(size_t)row * 512 + 256 + tid] + fb[256 + tid]);
    float fused = g0 * f + g1 * bw;
    __shared__ float red[256];
    red[tid] = fused;
    __syncthreads();
    for (int s = 128; s > 0; s >>= 1) {
        if (tid < s) red[tid] += red[tid + s];
        __syncthreads();
    }
    float mu = red[0] / (float)DMODEL;
    __syncthreads();
    float d = fused - mu;
    red[tid] = d * d;
    __syncthreads();
    for (int s = 128; s > 0; s >>= 1) {
        if (tid < s) red[tid] += red[tid + s];
        __syncthreads();
    }
    float var = red[0] / (float)DMODEL;
    out[(size_t)row * DMODEL + tid] = d * (1.0f / sqrtf(var + EPSF)) * lnw[tid] + lnb[tid];
}

// ---------------------------------------------------------------- launch
extern "C" void kernel_launch(void* const* d_in, const int* in_sizes, int n_in,
                              void* d_out, int out_size, void* d_ws, size_t ws_size,
                              hipStream_t stream) {
    const int*   ids  = (const int*)d_in[0];
    const float* mask = (const float*)d_in[1];
    const float* tok  = (const float*)d_in[2];
    const float* pos  = (const float*)d_in[3];
    const float* inw  = (const float*)d_in[4];
    const float* cw   = (const float*)d_in[5];
    const float* cb   = (const float*)d_in[6];
    const float* dtb  = (const float*)d_in[7];
    const float* alog = (const float*)d_in[8];
    const float* dpar = (const float*)d_in[9];
    const float* nw   = (const float*)d_in[10];
    const float* ow   = (const float*)d_in[11];
    const float* fw   = (const float*)d_in[12];
    const float* fb   = (const float*)d_in[13];
    const float* lnw  = (const float*)d_in[14];
    const float* lnb  = (const float*)d_in[15];

    float* ws   = (float*)d_ws;
    float* ubuf = ws;                                        // 2*2048*256  = 1,048,576 f
    float* zbuf = ubuf + (size_t)2 * ROWS * DMODEL;          // 2*2048*512  = 2,097,152 f
    float* xbc  = zbuf + (size_t)2 * ROWS * DINNER;          // 2*2048*648  = 2,654,208 f
    float* xc   = xbc  + (size_t)2 * ROWS * XBCW;            // 2*2048*640  = 2,621,440 f
    float* dts  = xc   + (size_t)2 * ROWS * CONVDIM;         // 2*2048*8
    float* ybuf = dts  + (size_t)2 * ROWS * NHEADS;          // 2*2048*512
    // overlays (regions dead at time of use):
    float* H    = xbc;                                       // 32*16*4096 = 2,097,152 f (xbc dead after conv)
    float* cumb = xbc + (size_t)32 * NC * 4096;              // 32*1024 (fits in xbc tail)
    float* comb = xc;                                        // 2048*512 (xc dead after scan of last layer)
    float* gate = xc + (size_t)ROWS * 512;                   // 2048*512

    embed_kernel<<<ROWS, DMODEL, 0, stream>>>(ids, mask, tok, pos, ubuf, ubuf + (size_t)ROWS * DMODEL);

    for (int layer = 0; layer < 2; ++layer) {
        dim3 g1(ROWS / BM, (DINPROJ + BN - 1) / BN, 2);
        gemm_nt<<<g1, 256, 0, stream>>>(ubuf, inw + (size_t)layer * DINPROJ * DMODEL,
                                        zbuf, xbc,
                                        ROWS, DINPROJ, DMODEL, DINNER, DINNER, XBCW,
                                        (long)ROWS * DMODEL, (long)2 * DINPROJ * DMODEL,
                                        (long)ROWS * DINNER, (long)ROWS * XBCW);
        conv_dt_kernel<<<dim3(ROWS, 2), 256, 0, stream>>>(xbc, xc, dts, cw, cb, dtb, layer);
        scan_chunk_kernel<<<32 * NC, 64, 0, stream>>>(xc, dts, ybuf, alog, dpar, H, cumb, layer);
        carry_kernel<<<32, 256, 0, stream>>>(H, cumb);
        fix_kernel<<<32 * (NC - 1), 64, 0, stream>>>(xc, ybuf, H, cumb);
        gate_rms_kernel<<<dim3(ROWS, 2), 256, 0, stream>>>(ybuf, zbuf, nw, layer);
        dim3 g2(ROWS / BM, DMODEL / BN, 2);
        gemm_nt<<<g2, 256, 0, stream>>>(ybuf, ow + (size_t)layer * DMODEL * DINNER,
                                        ubuf, ubuf,
                                        ROWS, DMODEL, DINNER, DMODEL, DMODEL, DMODEL,
                                        (long)ROWS * DINNER, (long)2 * DMODEL * DINNER,
                                        (long)ROWS * DMODEL, (long)ROWS * DMODEL);
    }

    concat_kernel<<<ROWS, 256, 0, stream>>>(ubuf, ubuf + (size_t)ROWS * DMODEL, comb);
    dim3 g3(ROWS / BM, 512 / BN, 1);
    gemm_nt<<<g3, 256, 0, stream>>>(comb, fw, gate, gate,
                                    ROWS, 512, 512, 512, 512, 512,
                                    0L, 0L, 0L, 0L);
    fusion_ln2_kernel<<<ROWS, 256, 0, stream>>>(comb, gate, fb, lnw, lnb, (float*)d_out);
}